// Round 1
// baseline (1456.531 us; speedup 1.0000x reference)
//
#include <hip/hip_runtime.h>
#include <math.h>

// TransformerConvNet: 2x TransformerConv(heads=1) + ELU + MLP head + log_softmax
// N=100000 nodes, E=1600000 edges, F_IN=64, C1=32, C2=64, H1=128, NC=10

// ---------- helpers: monotone float <-> uint encoding for atomicMax ----------
__device__ __forceinline__ unsigned fenc(float f) {
    unsigned u = __float_as_uint(f);
    return (u & 0x80000000u) ? ~u : (u | 0x80000000u);
}
__device__ __forceinline__ float fdec(unsigned u) {
    return __uint_as_float((u & 0x80000000u) ? (u ^ 0x80000000u) : ~u);
}

// ---------- fused 4-way linear: q/k/v/s = X @ {Wq,Wk,Wv,Ws} + b ----------
template<int FIN, int C>
__global__ __launch_bounds__(256)
void linear4_kernel(const float* __restrict__ X,
                    const float* __restrict__ Wq, const float* __restrict__ bq,
                    const float* __restrict__ Wk, const float* __restrict__ bk,
                    const float* __restrict__ Wv, const float* __restrict__ bv,
                    const float* __restrict__ Ws, const float* __restrict__ bs,
                    float* __restrict__ q, float* __restrict__ kk,
                    float* __restrict__ v, float* __restrict__ s, int n)
{
    constexpr int FOURC = 4 * C;
    __shared__ float wsh[FIN * FOURC];
    __shared__ float bsh[FOURC];
    {
        const float* Wm[4] = {Wq, Wk, Wv, Ws};
        for (int i = threadIdx.x; i < FIN * C; i += 256) {
            int f = i / C, c = i - (i / C) * C;
            #pragma unroll
            for (int m = 0; m < 4; ++m) wsh[f * FOURC + m * C + c] = Wm[m][i];
        }
        const float* bm[4] = {bq, bk, bv, bs};
        for (int i = threadIdx.x; i < FOURC; i += 256) bsh[i] = bm[i / C][i - (i / C) * C];
    }
    __syncthreads();
    const int total = n * FOURC;
    for (int idx = blockIdx.x * 256 + threadIdx.x; idx < total; idx += gridDim.x * 256) {
        int row = idx / FOURC;
        int cc  = idx - row * FOURC;
        const float* xr = X + (size_t)row * FIN;
        float acc = bsh[cc];
        #pragma unroll
        for (int f = 0; f < FIN; ++f) acc = fmaf(xr[f], wsh[f * FOURC + cc], acc);
        int m = cc / C, col = cc - (cc / C) * C;
        float* op = (m == 0) ? q : (m == 1) ? kk : (m == 2) ? v : s;
        op[(size_t)row * C + col] = acc;
    }
}

// ---------- per-edge attention logit + segment max (atomicMax on encoded f32) ----------
template<int C>
__global__ __launch_bounds__(256)
void edge_alpha_kernel(const int* __restrict__ src, const int* __restrict__ dst,
                       const float* __restrict__ eattr,
                       const float* __restrict__ q, const float* __restrict__ k,
                       const float* __restrict__ We, const float* __restrict__ be,
                       float* __restrict__ alpha, unsigned* __restrict__ mEnc,
                       float scale, int e)
{
    __shared__ float we[C], bb[C];
    for (int i = threadIdx.x; i < C; i += 256) { we[i] = We[i]; bb[i] = be[i]; }
    __syncthreads();
    for (int idx = blockIdx.x * 256 + threadIdx.x; idx < e; idx += gridDim.x * 256) {
        int sN = src[idx], dN = dst[idx];
        float a = eattr[idx];
        const float* qr = q + (size_t)dN * C;
        const float* kr = k + (size_t)sN * C;
        float acc = 0.f;
        #pragma unroll
        for (int c = 0; c < C; ++c) acc += qr[c] * (kr[c] + fmaf(a, we[c], bb[c]));
        float al = acc * scale;
        alpha[idx] = al;
        atomicMax(mEnc + dN, fenc(al));
    }
}

// ---------- per-edge exp(alpha - max) + segment sum ----------
__global__ __launch_bounds__(256)
void edge_exp_kernel(const int* __restrict__ dst, float* __restrict__ alpha,
                     const unsigned* __restrict__ mEnc, float* __restrict__ ssum, int e)
{
    for (int idx = blockIdx.x * 256 + threadIdx.x; idx < e; idx += gridDim.x * 256) {
        int dN = dst[idx];
        float a = __expf(alpha[idx] - fdec(mEnc[dN]));
        alpha[idx] = a;   // overwrite logit with unnormalized weight
        atomicAdd(ssum + dN, a);
    }
}

// ---------- per-(edge,channel) weighted value scatter ----------
template<int C>
__global__ __launch_bounds__(256)
void edge_scatter_kernel(const int* __restrict__ src, const int* __restrict__ dst,
                         const float* __restrict__ eattr, const float* __restrict__ a,
                         const float* __restrict__ ssum, const float* __restrict__ v,
                         const float* __restrict__ We, const float* __restrict__ be,
                         float* __restrict__ agg, int e)
{
    __shared__ float we[C], bb[C];
    for (int i = threadIdx.x; i < C; i += 256) { we[i] = We[i]; bb[i] = be[i]; }
    __syncthreads();
    const long total = (long)e * C;
    for (long idx = (long)blockIdx.x * 256 + threadIdx.x; idx < total;
         idx += (long)gridDim.x * 256) {
        int ei = (int)(idx / C);
        int c  = (int)(idx - (long)ei * C);
        int dN = dst[ei], sN = src[ei];
        float w = a[ei] / (ssum[dN] + 1e-16f);
        float val = v[(size_t)sN * C + c] + fmaf(eattr[ei], we[c], bb[c]);
        atomicAdd(agg + (size_t)dN * C + c, w * val);
    }
}

// ---------- h = elu(agg + skip) ----------
__global__ __launch_bounds__(256)
void finalize_kernel(const float* __restrict__ agg, const float* __restrict__ s,
                     float* __restrict__ h, int total)
{
    for (int idx = blockIdx.x * 256 + threadIdx.x; idx < total; idx += gridDim.x * 256) {
        float x = agg[idx] + s[idx];
        h[idx] = (x > 0.f) ? x : expm1f(x);
    }
}

// ---------- single linear (+ optional ELU) ----------
template<int FIN, int COUT, bool ELU>
__global__ __launch_bounds__(256)
void linear1_kernel(const float* __restrict__ X, const float* __restrict__ W,
                    const float* __restrict__ b, float* __restrict__ out, int n)
{
    __shared__ float wsh[FIN * COUT];
    __shared__ float bsh[COUT];
    for (int i = threadIdx.x; i < FIN * COUT; i += 256) wsh[i] = W[i];
    for (int i = threadIdx.x; i < COUT; i += 256) bsh[i] = b[i];
    __syncthreads();
    const int total = n * COUT;
    for (int idx = blockIdx.x * 256 + threadIdx.x; idx < total; idx += gridDim.x * 256) {
        int row = idx / COUT;
        int c   = idx - row * COUT;
        const float* xr = X + (size_t)row * FIN;
        float acc = bsh[c];
        #pragma unroll
        for (int f = 0; f < FIN; ++f) acc = fmaf(xr[f], wsh[f * COUT + c], acc);
        if (ELU) acc = (acc > 0.f) ? acc : expm1f(acc);
        out[(size_t)row * COUT + c] = acc;
    }
}

// ---------- fc2 + log_softmax ----------
#define H1_DIM 128
#define NC_DIM 10
__global__ __launch_bounds__(256)
void head_kernel(const float* __restrict__ Hf, const float* __restrict__ W,
                 const float* __restrict__ b, float* __restrict__ out, int n)
{
    __shared__ float wsh[H1_DIM * NC_DIM];
    __shared__ float bsh[NC_DIM];
    for (int i = threadIdx.x; i < H1_DIM * NC_DIM; i += 256) wsh[i] = W[i];
    for (int i = threadIdx.x; i < NC_DIM; i += 256) bsh[i] = b[i];
    __syncthreads();
    for (int row = blockIdx.x * 256 + threadIdx.x; row < n; row += gridDim.x * 256) {
        const float* hr = Hf + (size_t)row * H1_DIM;
        float logit[NC_DIM];
        #pragma unroll
        for (int c = 0; c < NC_DIM; ++c) logit[c] = bsh[c];
        for (int f = 0; f < H1_DIM; ++f) {
            float xv = hr[f];
            #pragma unroll
            for (int c = 0; c < NC_DIM; ++c) logit[c] = fmaf(xv, wsh[f * NC_DIM + c], logit[c]);
        }
        float m = logit[0];
        #pragma unroll
        for (int c = 1; c < NC_DIM; ++c) m = fmaxf(m, logit[c]);
        float sum = 0.f;
        #pragma unroll
        for (int c = 0; c < NC_DIM; ++c) sum += __expf(logit[c] - m);
        float lse = m + logf(sum);
        #pragma unroll
        for (int c = 0; c < NC_DIM; ++c) out[(size_t)row * NC_DIM + c] = logit[c] - lse;
    }
}

extern "C" void kernel_launch(void* const* d_in, const int* in_sizes, int n_in,
                              void* d_out, int out_size, void* d_ws, size_t ws_size,
                              hipStream_t stream) {
    const float* x   = (const float*)d_in[0];
    const int*   ei  = (const int*)d_in[1];
    const float* ea  = (const float*)d_in[2];
    const float *Wq1 = (const float*)d_in[3],  *bq1 = (const float*)d_in[4];
    const float *Wk1 = (const float*)d_in[5],  *bk1 = (const float*)d_in[6];
    const float *Wv1 = (const float*)d_in[7],  *bv1 = (const float*)d_in[8];
    const float *We1 = (const float*)d_in[9],  *be1 = (const float*)d_in[10];
    const float *Ws1 = (const float*)d_in[11], *bs1 = (const float*)d_in[12];
    const float *Wq2 = (const float*)d_in[13], *bq2 = (const float*)d_in[14];
    const float *Wk2 = (const float*)d_in[15], *bk2 = (const float*)d_in[16];
    const float *Wv2 = (const float*)d_in[17], *bv2 = (const float*)d_in[18];
    const float *We2 = (const float*)d_in[19], *be2 = (const float*)d_in[20];
    const float *Ws2 = (const float*)d_in[21], *bs2 = (const float*)d_in[22];
    const float *Wf1 = (const float*)d_in[23], *bf1 = (const float*)d_in[24];
    const float *Wf2 = (const float*)d_in[25], *bf2 = (const float*)d_in[26];

    const int N = in_sizes[0] / 64;   // 100000
    const int E = in_sizes[2];        // 1600000
    const int* src = ei;              // edge_index[0]
    const int* dst = ei + E;          // edge_index[1]

    float* wsf = (float*)d_ws;
    const size_t N64 = (size_t)N * 64;
    float* q     = wsf;                       // N*64
    float* k     = q + N64;                   // N*64
    float* v     = k + N64;                   // N*64
    float* s     = v + N64;                   // N*64 (skip proj)
    float* agg   = s + N64;                   // N*64 (message accumulator)
    float* h1    = agg + N64;                 // N*32
    float* h2    = h1 + (size_t)N * 32;       // N*64
    float* alpha = h2 + N64;                  // E
    unsigned* mEnc = (unsigned*)(alpha + E);  // N
    float* ssum  = (float*)(mEnc + N);        // N
    float* hfc   = wsf;                       // N*128 (reuses dead q|k after layer 2)

    float* out = (float*)d_out;

    // ================= layer 1 (C=32) =================
    hipMemsetAsync(mEnc, 0, (size_t)N * 8, stream);             // mEnc + ssum
    hipMemsetAsync(agg, 0, (size_t)N * 32 * 4, stream);
    linear4_kernel<64, 32><<<2048, 256, 0, stream>>>(
        x, Wq1, bq1, Wk1, bk1, Wv1, bv1, Ws1, bs1, q, k, v, s, N);
    edge_alpha_kernel<32><<<4096, 256, 0, stream>>>(
        src, dst, ea, q, k, We1, be1, alpha, mEnc, 0.17677669529663687f, E);
    edge_exp_kernel<<<4096, 256, 0, stream>>>(dst, alpha, mEnc, ssum, E);
    edge_scatter_kernel<32><<<8192, 256, 0, stream>>>(
        src, dst, ea, alpha, ssum, v, We1, be1, agg, E);
    finalize_kernel<<<4096, 256, 0, stream>>>(agg, s, h1, N * 32);

    // ================= layer 2 (C=64) =================
    hipMemsetAsync(mEnc, 0, (size_t)N * 8, stream);
    hipMemsetAsync(agg, 0, (size_t)N * 64 * 4, stream);
    linear4_kernel<32, 64><<<2048, 256, 0, stream>>>(
        h1, Wq2, bq2, Wk2, bk2, Wv2, bv2, Ws2, bs2, q, k, v, s, N);
    edge_alpha_kernel<64><<<4096, 256, 0, stream>>>(
        src, dst, ea, q, k, We2, be2, alpha, mEnc, 0.125f, E);
    edge_exp_kernel<<<4096, 256, 0, stream>>>(dst, alpha, mEnc, ssum, E);
    edge_scatter_kernel<64><<<8192, 256, 0, stream>>>(
        src, dst, ea, alpha, ssum, v, We2, be2, agg, E);
    finalize_kernel<<<4096, 256, 0, stream>>>(agg, s, h2, N * 64);

    // ================= MLP head =================
    linear1_kernel<64, 128, true><<<2048, 256, 0, stream>>>(h2, Wf1, bf1, hfc, N);
    head_kernel<<<512, 256, 0, stream>>>(hfc, Wf2, bf2, out, N);
}

// Round 2
// 1067.616 us; speedup vs baseline: 1.3643x; 1.3643x over previous
//
#include <hip/hip_runtime.h>
#include <math.h>

// TransformerConvNet: 2x TransformerConv(heads=1) + ELU + MLP head + log_softmax
// N=100000 nodes, E=1600000 edges, F_IN=64, C1=32, C2=64, H1=128, NC=10
//
// Strategy (R2): zero float atomics. Build dst-CSR once per call
// (count -> single-block scan -> fill with packed {src,eattr}), then one
// fused wave-per-node kernel per conv layer doing online softmax + weighted
// aggregation + skip + ELU entirely in registers.

// ---------- CSR build ----------
__global__ __launch_bounds__(256)
void count_deg_kernel(const int* __restrict__ dst, int* __restrict__ deg, int e) {
    for (int i = blockIdx.x * 256 + threadIdx.x; i < e; i += gridDim.x * 256)
        atomicAdd(deg + dst[i], 1);
}

__global__ __launch_bounds__(1024)
void scan_kernel(const int* __restrict__ deg, int* __restrict__ rowptr,
                 int* __restrict__ cursor, int n) {
    __shared__ int ls[1024];
    const int t = threadIdx.x;
    const int chunk = (n + 1023) / 1024;
    const int begin = t * chunk;
    const int end = (begin + chunk < n) ? begin + chunk : n;
    int sum = 0;
    for (int i = begin; i < end; ++i) sum += deg[i];
    ls[t] = sum;
    __syncthreads();
    for (int off = 1; off < 1024; off <<= 1) {
        int vv = (t >= off) ? ls[t - off] : 0;
        __syncthreads();
        ls[t] += vv;
        __syncthreads();
    }
    int run = ls[t] - sum;  // exclusive prefix for this thread's chunk
    for (int i = begin; i < end; ++i) {
        rowptr[i] = run; cursor[i] = run; run += deg[i];
    }
    if (t == 1023) rowptr[n] = ls[1023];
}

__global__ __launch_bounds__(256)
void fill_kernel(const int* __restrict__ src, const int* __restrict__ dst,
                 const float* __restrict__ eattr, int* __restrict__ cursor,
                 int* __restrict__ esrc, float* __restrict__ eatt, int e) {
    for (int i = blockIdx.x * 256 + threadIdx.x; i < e; i += gridDim.x * 256) {
        int p = atomicAdd(cursor + dst[i], 1);
        esrc[p] = src[i];
        eatt[p] = eattr[i];
    }
}

// ---------- fused 4-way linear: q/k/v/s = X @ {Wq,Wk,Wv,Ws} + b ----------
template<int FIN, int C>
__global__ __launch_bounds__(256)
void linear4_kernel(const float* __restrict__ X,
                    const float* __restrict__ Wq, const float* __restrict__ bq,
                    const float* __restrict__ Wk, const float* __restrict__ bk,
                    const float* __restrict__ Wv, const float* __restrict__ bv,
                    const float* __restrict__ Ws, const float* __restrict__ bs,
                    float* __restrict__ q, float* __restrict__ kk,
                    float* __restrict__ v, float* __restrict__ s, int n)
{
    constexpr int FOURC = 4 * C;
    __shared__ float wsh[FIN * FOURC];
    __shared__ float bsh[FOURC];
    {
        const float* Wm[4] = {Wq, Wk, Wv, Ws};
        for (int i = threadIdx.x; i < FIN * C; i += 256) {
            int f = i / C, c = i - (i / C) * C;
            #pragma unroll
            for (int m = 0; m < 4; ++m) wsh[f * FOURC + m * C + c] = Wm[m][i];
        }
        const float* bm[4] = {bq, bk, bv, bs};
        for (int i = threadIdx.x; i < FOURC; i += 256) bsh[i] = bm[i / C][i - (i / C) * C];
    }
    __syncthreads();
    const int total = n * FOURC;
    for (int idx = blockIdx.x * 256 + threadIdx.x; idx < total; idx += gridDim.x * 256) {
        int row = idx / FOURC;
        int cc  = idx - row * FOURC;
        const float* xr = X + (size_t)row * FIN;
        float acc = bsh[cc];
        #pragma unroll
        for (int f = 0; f < FIN; ++f) acc = fmaf(xr[f], wsh[f * FOURC + cc], acc);
        int m = cc / C, col = cc - (cc / C) * C;
        float* op = (m == 0) ? q : (m == 1) ? kk : (m == 2) ? v : s;
        op[(size_t)row * C + col] = acc;
    }
}

// ---------- fused conv: per-node online softmax + aggregation + skip + ELU ----------
template<int C>
__global__ __launch_bounds__(256)
void conv_fused_kernel(const int* __restrict__ rowptr, const int* __restrict__ esrc,
                       const float* __restrict__ eatt,
                       const float* __restrict__ q, const float* __restrict__ k,
                       const float* __restrict__ v, const float* __restrict__ sres,
                       const float* __restrict__ We, const float* __restrict__ be,
                       float* __restrict__ h, float scale, int n)
{
    constexpr int EPI = 64 / C;          // edges per wave iteration
    constexpr int LOGC = (C == 64) ? 6 : 5;
    const int wave = threadIdx.x >> 6;
    const int lane = threadIdx.x & 63;
    const int c    = lane & (C - 1);
    const int slot = lane >> LOGC;       // 0 for C=64; 0/1 for C=32
    const int node = blockIdx.x * 4 + wave;
    if (node >= n) return;

    const float wec = We[c], bec = be[c];
    const float qc  = q[(size_t)node * C + c];
    const int r0 = rowptr[node], r1 = rowptr[node + 1];

    float m = -INFINITY, ssum = 0.f, acc = 0.f;
    for (int j = r0 + slot; j < r1; j += EPI) {
        int   sN = esrc[j];
        float ea = eatt[j];
        float ec = fmaf(ea, wec, bec);
        float kc = k[(size_t)sN * C + c] + ec;
        float vc = v[(size_t)sN * C + c] + ec;
        float p = qc * kc;
        #pragma unroll
        for (int off = C >> 1; off > 0; off >>= 1)
            p += __shfl_xor(p, off, C);
        float alpha = p * scale;
        float nm = fmaxf(m, alpha);
        float so = __expf(m - nm);       // m=-inf, nm finite -> 0 (first edge)
        float pe = __expf(alpha - nm);
        ssum = ssum * so + pe;
        acc  = acc  * so + pe * vc;
        m = nm;
    }

    if constexpr (EPI == 2) {            // merge the two edge streams
        float m2 = __shfl_xor(m, 32);
        float s2 = __shfl_xor(ssum, 32);
        float a2 = __shfl_xor(acc, 32);
        float nm = fmaxf(m, m2);
        float e1 = (m  == -INFINITY) ? 0.f : __expf(m  - nm);
        float e2 = (m2 == -INFINITY) ? 0.f : __expf(m2 - nm);
        ssum = ssum * e1 + s2 * e2;
        acc  = acc  * e1 + a2 * e2;
    }

    if (slot == 0) {
        float outv = acc / (ssum + 1e-16f);
        float hv = outv + sres[(size_t)node * C + c];
        h[(size_t)node * C + c] = (hv > 0.f) ? hv : expm1f(hv);
    }
}

// ---------- single linear (+ optional ELU) ----------
template<int FIN, int COUT, bool ELU>
__global__ __launch_bounds__(256)
void linear1_kernel(const float* __restrict__ X, const float* __restrict__ W,
                    const float* __restrict__ b, float* __restrict__ out, int n)
{
    __shared__ float wsh[FIN * COUT];
    __shared__ float bsh[COUT];
    for (int i = threadIdx.x; i < FIN * COUT; i += 256) wsh[i] = W[i];
    for (int i = threadIdx.x; i < COUT; i += 256) bsh[i] = b[i];
    __syncthreads();
    const int total = n * COUT;
    for (int idx = blockIdx.x * 256 + threadIdx.x; idx < total; idx += gridDim.x * 256) {
        int row = idx / COUT;
        int c   = idx - row * COUT;
        const float* xr = X + (size_t)row * FIN;
        float acc = bsh[c];
        #pragma unroll
        for (int f = 0; f < FIN; ++f) acc = fmaf(xr[f], wsh[f * COUT + c], acc);
        if (ELU) acc = (acc > 0.f) ? acc : expm1f(acc);
        out[(size_t)row * COUT + c] = acc;
    }
}

// ---------- fc2 + log_softmax ----------
#define H1_DIM 128
#define NC_DIM 10
__global__ __launch_bounds__(256)
void head_kernel(const float* __restrict__ Hf, const float* __restrict__ W,
                 const float* __restrict__ b, float* __restrict__ out, int n)
{
    __shared__ float wsh[H1_DIM * NC_DIM];
    __shared__ float bsh[NC_DIM];
    for (int i = threadIdx.x; i < H1_DIM * NC_DIM; i += 256) wsh[i] = W[i];
    for (int i = threadIdx.x; i < NC_DIM; i += 256) bsh[i] = b[i];
    __syncthreads();
    for (int row = blockIdx.x * 256 + threadIdx.x; row < n; row += gridDim.x * 256) {
        const float* hr = Hf + (size_t)row * H1_DIM;
        float logit[NC_DIM];
        #pragma unroll
        for (int c = 0; c < NC_DIM; ++c) logit[c] = bsh[c];
        for (int f = 0; f < H1_DIM; ++f) {
            float xv = hr[f];
            #pragma unroll
            for (int c = 0; c < NC_DIM; ++c) logit[c] = fmaf(xv, wsh[f * NC_DIM + c], logit[c]);
        }
        float m = logit[0];
        #pragma unroll
        for (int c = 1; c < NC_DIM; ++c) m = fmaxf(m, logit[c]);
        float sum = 0.f;
        #pragma unroll
        for (int c = 0; c < NC_DIM; ++c) sum += __expf(logit[c] - m);
        float lse = m + logf(sum);
        #pragma unroll
        for (int c = 0; c < NC_DIM; ++c) out[(size_t)row * NC_DIM + c] = logit[c] - lse;
    }
}

extern "C" void kernel_launch(void* const* d_in, const int* in_sizes, int n_in,
                              void* d_out, int out_size, void* d_ws, size_t ws_size,
                              hipStream_t stream) {
    const float* x   = (const float*)d_in[0];
    const int*   ei  = (const int*)d_in[1];
    const float* ea  = (const float*)d_in[2];
    const float *Wq1 = (const float*)d_in[3],  *bq1 = (const float*)d_in[4];
    const float *Wk1 = (const float*)d_in[5],  *bk1 = (const float*)d_in[6];
    const float *Wv1 = (const float*)d_in[7],  *bv1 = (const float*)d_in[8];
    const float *We1 = (const float*)d_in[9],  *be1 = (const float*)d_in[10];
    const float *Ws1 = (const float*)d_in[11], *bs1 = (const float*)d_in[12];
    const float *Wq2 = (const float*)d_in[13], *bq2 = (const float*)d_in[14];
    const float *Wk2 = (const float*)d_in[15], *bk2 = (const float*)d_in[16];
    const float *Wv2 = (const float*)d_in[17], *bv2 = (const float*)d_in[18];
    const float *We2 = (const float*)d_in[19], *be2 = (const float*)d_in[20];
    const float *Ws2 = (const float*)d_in[21], *bs2 = (const float*)d_in[22];
    const float *Wf1 = (const float*)d_in[23], *bf1 = (const float*)d_in[24];
    const float *Wf2 = (const float*)d_in[25], *bf2 = (const float*)d_in[26];

    const int N = in_sizes[0] / 64;   // 100000
    const int E = in_sizes[2];        // 1600000
    const int* src = ei;              // edge_index[0]
    const int* dst = ei + E;          // edge_index[1]

    float* wsf = (float*)d_ws;
    const size_t N64 = (size_t)N * 64;
    float* q   = wsf;                        // N*64
    float* k   = q + N64;                    // N*64
    float* v   = k + N64;                    // N*64
    float* s   = v + N64;                    // N*64 (skip proj)
    float* h1  = s + N64;                    // N*32
    float* h2  = h1 + (size_t)N * 32;        // N*64
    int* deg     = (int*)(h2 + N64);         // N
    int* rowptr  = deg + N;                  // N+1
    int* cursor  = rowptr + N + 1;           // N
    int* esrc    = cursor + N;               // E
    float* eatt  = (float*)(esrc + E);       // E
    float* hfc   = wsf;                      // N*128 (reuses dead q|k after conv2)

    float* out = (float*)d_out;

    // ---- CSR build (graph identical for both layers; rebuilt every call) ----
    hipMemsetAsync(deg, 0, (size_t)N * 4, stream);
    count_deg_kernel<<<2048, 256, 0, stream>>>(dst, deg, E);
    scan_kernel<<<1, 1024, 0, stream>>>(deg, rowptr, cursor, N);
    fill_kernel<<<4096, 256, 0, stream>>>(src, dst, ea, cursor, esrc, eatt, E);

    const int convGrid = (N + 3) / 4;

    // ---- layer 1 (C=32) ----
    linear4_kernel<64, 32><<<2048, 256, 0, stream>>>(
        x, Wq1, bq1, Wk1, bk1, Wv1, bv1, Ws1, bs1, q, k, v, s, N);
    conv_fused_kernel<32><<<convGrid, 256, 0, stream>>>(
        rowptr, esrc, eatt, q, k, v, s, We1, be1, h1, 0.17677669529663687f, N);

    // ---- layer 2 (C=64) ----
    linear4_kernel<32, 64><<<2048, 256, 0, stream>>>(
        h1, Wq2, bq2, Wk2, bk2, Wv2, bv2, Ws2, bs2, q, k, v, s, N);
    conv_fused_kernel<64><<<convGrid, 256, 0, stream>>>(
        rowptr, esrc, eatt, q, k, v, s, We2, be2, h2, 0.125f, N);

    // ---- MLP head ----
    linear1_kernel<64, 128, true><<<2048, 256, 0, stream>>>(h2, Wf1, bf1, hfc, N);
    head_kernel<<<512, 256, 0, stream>>>(hfc, Wf2, bf2, out, N);
}

// Round 3
// 854.161 us; speedup vs baseline: 1.7052x; 1.2499x over previous
//
#include <hip/hip_runtime.h>
#include <math.h>

// TransformerConvNet: 2x TransformerConv(heads=1) + ELU + MLP head + log_softmax
// N=100000 nodes, E=1600000 edges, F_IN=64, C1=32, C2=64, H1=128, NC=10
//
// R3: replace single-block scan (230 us, latency-bound) with 3-phase
// hierarchical scan across 256 blocks.

#define SCAN_NB 256

// ---------- CSR build ----------
__global__ __launch_bounds__(256)
void count_deg_kernel(const int* __restrict__ dst, int* __restrict__ deg, int e) {
    for (int i = blockIdx.x * 256 + threadIdx.x; i < e; i += gridDim.x * 256)
        atomicAdd(deg + dst[i], 1);
}

// phase 1: per-block sums of deg over contiguous block ranges
__global__ __launch_bounds__(256)
void blocksum_kernel(const int* __restrict__ deg, int* __restrict__ bsum, int n) {
    __shared__ int ls[256];
    const int chunk = (n + gridDim.x - 1) / gridDim.x;
    const int b0 = blockIdx.x * chunk;
    const int b1 = (b0 + chunk < n) ? b0 + chunk : n;
    int s = 0;
    for (int i = b0 + threadIdx.x; i < b1; i += 256) s += deg[i];
    ls[threadIdx.x] = s;
    __syncthreads();
    for (int off = 128; off > 0; off >>= 1) {
        if (threadIdx.x < off) ls[threadIdx.x] += ls[threadIdx.x + off];
        __syncthreads();
    }
    if (threadIdx.x == 0) bsum[blockIdx.x] = ls[0];
}

// phase 2: exclusive scan of the <=256 block sums (single tiny block)
__global__ __launch_bounds__(256)
void scanb_kernel(const int* __restrict__ bsum, int* __restrict__ boff,
                  int* __restrict__ total, int nb) {
    __shared__ int ls[256];
    const int t = threadIdx.x;
    int v = (t < nb) ? bsum[t] : 0;
    ls[t] = v;
    __syncthreads();
    for (int off = 1; off < 256; off <<= 1) {
        int u = (t >= off) ? ls[t - off] : 0;
        __syncthreads();
        ls[t] += u;
        __syncthreads();
    }
    if (t < nb) boff[t] = ls[t] - v;       // exclusive prefix
    if (t == 255) *total = ls[255];        // rowptr[n] = E
}

// phase 3: per-block local exclusive scan + rowptr/cursor write
__global__ __launch_bounds__(256)
void writeptr_kernel(const int* __restrict__ deg, const int* __restrict__ boff,
                     int* __restrict__ rowptr, int* __restrict__ cursor, int n) {
    __shared__ int ls[256];
    const int chunk = (n + gridDim.x - 1) / gridDim.x;
    const int b0 = blockIdx.x * chunk;
    const int b1 = (b0 + chunk < n) ? b0 + chunk : n;
    const int tchunk = (chunk + 255) / 256;
    const int t0 = b0 + threadIdx.x * tchunk;
    const int t1 = (t0 + tchunk < b1) ? t0 + tchunk : b1;
    int s = 0;
    for (int i = t0; i < t1; ++i) s += deg[i];
    ls[threadIdx.x] = s;
    __syncthreads();
    for (int off = 1; off < 256; off <<= 1) {
        int u = (threadIdx.x >= off) ? ls[threadIdx.x - off] : 0;
        __syncthreads();
        ls[threadIdx.x] += u;
        __syncthreads();
    }
    int run = boff[blockIdx.x] + ls[threadIdx.x] - s;   // exclusive within grid
    for (int i = t0; i < t1; ++i) {
        rowptr[i] = run; cursor[i] = run; run += deg[i];
    }
}

__global__ __launch_bounds__(256)
void fill_kernel(const int* __restrict__ src, const int* __restrict__ dst,
                 const float* __restrict__ eattr, int* __restrict__ cursor,
                 int* __restrict__ esrc, float* __restrict__ eatt, int e) {
    for (int i = blockIdx.x * 256 + threadIdx.x; i < e; i += gridDim.x * 256) {
        int p = atomicAdd(cursor + dst[i], 1);
        esrc[p] = src[i];
        eatt[p] = eattr[i];
    }
}

// ---------- fused 4-way linear: q/k/v/s = X @ {Wq,Wk,Wv,Ws} + b ----------
template<int FIN, int C>
__global__ __launch_bounds__(256)
void linear4_kernel(const float* __restrict__ X,
                    const float* __restrict__ Wq, const float* __restrict__ bq,
                    const float* __restrict__ Wk, const float* __restrict__ bk,
                    const float* __restrict__ Wv, const float* __restrict__ bv,
                    const float* __restrict__ Ws, const float* __restrict__ bs,
                    float* __restrict__ q, float* __restrict__ kk,
                    float* __restrict__ v, float* __restrict__ s, int n)
{
    constexpr int FOURC = 4 * C;
    __shared__ float wsh[FIN * FOURC];
    __shared__ float bsh[FOURC];
    {
        const float* Wm[4] = {Wq, Wk, Wv, Ws};
        for (int i = threadIdx.x; i < FIN * C; i += 256) {
            int f = i / C, c = i - (i / C) * C;
            #pragma unroll
            for (int m = 0; m < 4; ++m) wsh[f * FOURC + m * C + c] = Wm[m][i];
        }
        const float* bm[4] = {bq, bk, bv, bs};
        for (int i = threadIdx.x; i < FOURC; i += 256) bsh[i] = bm[i / C][i - (i / C) * C];
    }
    __syncthreads();
    const int total = n * FOURC;
    for (int idx = blockIdx.x * 256 + threadIdx.x; idx < total; idx += gridDim.x * 256) {
        int row = idx / FOURC;
        int cc  = idx - row * FOURC;
        const float* xr = X + (size_t)row * FIN;
        float acc = bsh[cc];
        #pragma unroll
        for (int f = 0; f < FIN; ++f) acc = fmaf(xr[f], wsh[f * FOURC + cc], acc);
        int m = cc / C, col = cc - (cc / C) * C;
        float* op = (m == 0) ? q : (m == 1) ? kk : (m == 2) ? v : s;
        op[(size_t)row * C + col] = acc;
    }
}

// ---------- fused conv: per-node online softmax + aggregation + skip + ELU ----------
template<int C>
__global__ __launch_bounds__(256)
void conv_fused_kernel(const int* __restrict__ rowptr, const int* __restrict__ esrc,
                       const float* __restrict__ eatt,
                       const float* __restrict__ q, const float* __restrict__ k,
                       const float* __restrict__ v, const float* __restrict__ sres,
                       const float* __restrict__ We, const float* __restrict__ be,
                       float* __restrict__ h, float scale, int n)
{
    constexpr int EPI = 64 / C;          // edges per wave iteration
    constexpr int LOGC = (C == 64) ? 6 : 5;
    const int wave = threadIdx.x >> 6;
    const int lane = threadIdx.x & 63;
    const int c    = lane & (C - 1);
    const int slot = lane >> LOGC;       // 0 for C=64; 0/1 for C=32
    const int node = blockIdx.x * 4 + wave;
    if (node >= n) return;

    const float wec = We[c], bec = be[c];
    const float qc  = q[(size_t)node * C + c];
    const int r0 = rowptr[node], r1 = rowptr[node + 1];

    float m = -INFINITY, ssum = 0.f, acc = 0.f;
    for (int j = r0 + slot; j < r1; j += EPI) {
        int   sN = esrc[j];
        float ea = eatt[j];
        float ec = fmaf(ea, wec, bec);
        float kc = k[(size_t)sN * C + c] + ec;
        float vc = v[(size_t)sN * C + c] + ec;
        float p = qc * kc;
        #pragma unroll
        for (int off = C >> 1; off > 0; off >>= 1)
            p += __shfl_xor(p, off, C);
        float alpha = p * scale;
        float nm = fmaxf(m, alpha);
        float so = __expf(m - nm);       // m=-inf, nm finite -> 0 (first edge)
        float pe = __expf(alpha - nm);
        ssum = ssum * so + pe;
        acc  = acc  * so + pe * vc;
        m = nm;
    }

    if constexpr (EPI == 2) {            // merge the two edge streams
        float m2 = __shfl_xor(m, 32);
        float s2 = __shfl_xor(ssum, 32);
        float a2 = __shfl_xor(acc, 32);
        float nm = fmaxf(m, m2);
        float e1 = (m  == -INFINITY) ? 0.f : __expf(m  - nm);
        float e2 = (m2 == -INFINITY) ? 0.f : __expf(m2 - nm);
        ssum = ssum * e1 + s2 * e2;
        acc  = acc  * e1 + a2 * e2;
    }

    if (slot == 0) {
        float outv = acc / (ssum + 1e-16f);
        float hv = outv + sres[(size_t)node * C + c];
        h[(size_t)node * C + c] = (hv > 0.f) ? hv : expm1f(hv);
    }
}

// ---------- single linear (+ optional ELU) ----------
template<int FIN, int COUT, bool ELU>
__global__ __launch_bounds__(256)
void linear1_kernel(const float* __restrict__ X, const float* __restrict__ W,
                    const float* __restrict__ b, float* __restrict__ out, int n)
{
    __shared__ float wsh[FIN * COUT];
    __shared__ float bsh[COUT];
    for (int i = threadIdx.x; i < FIN * COUT; i += 256) wsh[i] = W[i];
    for (int i = threadIdx.x; i < COUT; i += 256) bsh[i] = b[i];
    __syncthreads();
    const int total = n * COUT;
    for (int idx = blockIdx.x * 256 + threadIdx.x; idx < total; idx += gridDim.x * 256) {
        int row = idx / COUT;
        int c   = idx - row * COUT;
        const float* xr = X + (size_t)row * FIN;
        float acc = bsh[c];
        #pragma unroll
        for (int f = 0; f < FIN; ++f) acc = fmaf(xr[f], wsh[f * COUT + c], acc);
        if (ELU) acc = (acc > 0.f) ? acc : expm1f(acc);
        out[(size_t)row * COUT + c] = acc;
    }
}

// ---------- fc2 + log_softmax ----------
#define H1_DIM 128
#define NC_DIM 10
__global__ __launch_bounds__(256)
void head_kernel(const float* __restrict__ Hf, const float* __restrict__ W,
                 const float* __restrict__ b, float* __restrict__ out, int n)
{
    __shared__ float wsh[H1_DIM * NC_DIM];
    __shared__ float bsh[NC_DIM];
    for (int i = threadIdx.x; i < H1_DIM * NC_DIM; i += 256) wsh[i] = W[i];
    for (int i = threadIdx.x; i < NC_DIM; i += 256) bsh[i] = b[i];
    __syncthreads();
    for (int row = blockIdx.x * 256 + threadIdx.x; row < n; row += gridDim.x * 256) {
        const float* hr = Hf + (size_t)row * H1_DIM;
        float logit[NC_DIM];
        #pragma unroll
        for (int c = 0; c < NC_DIM; ++c) logit[c] = bsh[c];
        for (int f = 0; f < H1_DIM; ++f) {
            float xv = hr[f];
            #pragma unroll
            for (int c = 0; c < NC_DIM; ++c) logit[c] = fmaf(xv, wsh[f * NC_DIM + c], logit[c]);
        }
        float m = logit[0];
        #pragma unroll
        for (int c = 1; c < NC_DIM; ++c) m = fmaxf(m, logit[c]);
        float sum = 0.f;
        #pragma unroll
        for (int c = 0; c < NC_DIM; ++c) sum += __expf(logit[c] - m);
        float lse = m + logf(sum);
        #pragma unroll
        for (int c = 0; c < NC_DIM; ++c) out[(size_t)row * NC_DIM + c] = logit[c] - lse;
    }
}

extern "C" void kernel_launch(void* const* d_in, const int* in_sizes, int n_in,
                              void* d_out, int out_size, void* d_ws, size_t ws_size,
                              hipStream_t stream) {
    const float* x   = (const float*)d_in[0];
    const int*   ei  = (const int*)d_in[1];
    const float* ea  = (const float*)d_in[2];
    const float *Wq1 = (const float*)d_in[3],  *bq1 = (const float*)d_in[4];
    const float *Wk1 = (const float*)d_in[5],  *bk1 = (const float*)d_in[6];
    const float *Wv1 = (const float*)d_in[7],  *bv1 = (const float*)d_in[8];
    const float *We1 = (const float*)d_in[9],  *be1 = (const float*)d_in[10];
    const float *Ws1 = (const float*)d_in[11], *bs1 = (const float*)d_in[12];
    const float *Wq2 = (const float*)d_in[13], *bq2 = (const float*)d_in[14];
    const float *Wk2 = (const float*)d_in[15], *bk2 = (const float*)d_in[16];
    const float *Wv2 = (const float*)d_in[17], *bv2 = (const float*)d_in[18];
    const float *We2 = (const float*)d_in[19], *be2 = (const float*)d_in[20];
    const float *Ws2 = (const float*)d_in[21], *bs2 = (const float*)d_in[22];
    const float *Wf1 = (const float*)d_in[23], *bf1 = (const float*)d_in[24];
    const float *Wf2 = (const float*)d_in[25], *bf2 = (const float*)d_in[26];

    const int N = in_sizes[0] / 64;   // 100000
    const int E = in_sizes[2];        // 1600000
    const int* src = ei;              // edge_index[0]
    const int* dst = ei + E;          // edge_index[1]

    float* wsf = (float*)d_ws;
    const size_t N64 = (size_t)N * 64;
    float* q   = wsf;                        // N*64
    float* k   = q + N64;                    // N*64
    float* v   = k + N64;                    // N*64
    float* s   = v + N64;                    // N*64 (skip proj)
    float* h1  = s + N64;                    // N*32
    float* h2  = h1 + (size_t)N * 32;        // N*64
    int* deg     = (int*)(h2 + N64);         // N
    int* rowptr  = deg + N;                  // N+1
    int* cursor  = rowptr + N + 1;           // N
    int* bsum    = cursor + N;               // SCAN_NB
    int* boff    = bsum + SCAN_NB;           // SCAN_NB
    int* esrc    = boff + SCAN_NB;           // E
    float* eatt  = (float*)(esrc + E);       // E
    float* hfc   = wsf;                      // N*128 (reuses dead q|k after conv2)

    float* out = (float*)d_out;

    // ---- CSR build (graph identical for both layers; rebuilt every call) ----
    hipMemsetAsync(deg, 0, (size_t)N * 4, stream);
    count_deg_kernel<<<2048, 256, 0, stream>>>(dst, deg, E);
    blocksum_kernel<<<SCAN_NB, 256, 0, stream>>>(deg, bsum, N);
    scanb_kernel<<<1, 256, 0, stream>>>(bsum, boff, rowptr + N, SCAN_NB);
    writeptr_kernel<<<SCAN_NB, 256, 0, stream>>>(deg, boff, rowptr, cursor, N);
    fill_kernel<<<4096, 256, 0, stream>>>(src, dst, ea, cursor, esrc, eatt, E);

    const int convGrid = (N + 3) / 4;

    // ---- layer 1 (C=32) ----
    linear4_kernel<64, 32><<<2048, 256, 0, stream>>>(
        x, Wq1, bq1, Wk1, bk1, Wv1, bv1, Ws1, bs1, q, k, v, s, N);
    conv_fused_kernel<32><<<convGrid, 256, 0, stream>>>(
        rowptr, esrc, eatt, q, k, v, s, We1, be1, h1, 0.17677669529663687f, N);

    // ---- layer 2 (C=64) ----
    linear4_kernel<32, 64><<<2048, 256, 0, stream>>>(
        h1, Wq2, bq2, Wk2, bk2, Wv2, bv2, Ws2, bs2, q, k, v, s, N);
    conv_fused_kernel<64><<<convGrid, 256, 0, stream>>>(
        rowptr, esrc, eatt, q, k, v, s, We2, be2, h2, 0.125f, N);

    // ---- MLP head ----
    linear1_kernel<64, 128, true><<<2048, 256, 0, stream>>>(h2, Wf1, bf1, hfc, N);
    head_kernel<<<512, 256, 0, stream>>>(hfc, Wf2, bf2, out, N);
}

// Round 4
// 726.474 us; speedup vs baseline: 2.0049x; 1.1758x over previous
//
#include <hip/hip_runtime.h>
#include <math.h>

// TransformerConvNet: 2x TransformerConv(heads=1) + ELU + MLP head + log_softmax
// N=100000 nodes, E=1600000 edges, F_IN=64, C1=32, C2=64, H1=128, NC=10
//
// R4: conv_fused latency fix — no-max softmax (shift-invariant, logits tiny),
// 4-deep independent gather pipeline, channel-interleaved kv float2 gathers.

#define SCAN_NB 256

// ---------- CSR build ----------
__global__ __launch_bounds__(256)
void count_deg_kernel(const int* __restrict__ dst, int* __restrict__ deg, int e) {
    for (int i = blockIdx.x * 256 + threadIdx.x; i < e; i += gridDim.x * 256)
        atomicAdd(deg + dst[i], 1);
}

__global__ __launch_bounds__(256)
void blocksum_kernel(const int* __restrict__ deg, int* __restrict__ bsum, int n) {
    __shared__ int ls[256];
    const int chunk = (n + gridDim.x - 1) / gridDim.x;
    const int b0 = blockIdx.x * chunk;
    const int b1 = (b0 + chunk < n) ? b0 + chunk : n;
    int s = 0;
    for (int i = b0 + threadIdx.x; i < b1; i += 256) s += deg[i];
    ls[threadIdx.x] = s;
    __syncthreads();
    for (int off = 128; off > 0; off >>= 1) {
        if (threadIdx.x < off) ls[threadIdx.x] += ls[threadIdx.x + off];
        __syncthreads();
    }
    if (threadIdx.x == 0) bsum[blockIdx.x] = ls[0];
}

__global__ __launch_bounds__(256)
void scanb_kernel(const int* __restrict__ bsum, int* __restrict__ boff,
                  int* __restrict__ total, int nb) {
    __shared__ int ls[256];
    const int t = threadIdx.x;
    int v = (t < nb) ? bsum[t] : 0;
    ls[t] = v;
    __syncthreads();
    for (int off = 1; off < 256; off <<= 1) {
        int u = (t >= off) ? ls[t - off] : 0;
        __syncthreads();
        ls[t] += u;
        __syncthreads();
    }
    if (t < nb) boff[t] = ls[t] - v;
    if (t == 255) *total = ls[255];
}

__global__ __launch_bounds__(256)
void writeptr_kernel(const int* __restrict__ deg, const int* __restrict__ boff,
                     int* __restrict__ rowptr, int* __restrict__ cursor, int n) {
    __shared__ int ls[256];
    const int chunk = (n + gridDim.x - 1) / gridDim.x;
    const int b0 = blockIdx.x * chunk;
    const int b1 = (b0 + chunk < n) ? b0 + chunk : n;
    const int tchunk = (chunk + 255) / 256;
    const int t0 = b0 + threadIdx.x * tchunk;
    const int t1 = (t0 + tchunk < b1) ? t0 + tchunk : b1;
    int s = 0;
    for (int i = t0; i < t1; ++i) s += deg[i];
    ls[threadIdx.x] = s;
    __syncthreads();
    for (int off = 1; off < 256; off <<= 1) {
        int u = (threadIdx.x >= off) ? ls[threadIdx.x - off] : 0;
        __syncthreads();
        ls[threadIdx.x] += u;
        __syncthreads();
    }
    int run = boff[blockIdx.x] + ls[threadIdx.x] - s;
    for (int i = t0; i < t1; ++i) {
        rowptr[i] = run; cursor[i] = run; run += deg[i];
    }
}

__global__ __launch_bounds__(256)
void fill_kernel(const int* __restrict__ src, const int* __restrict__ dst,
                 const float* __restrict__ eattr, int* __restrict__ cursor,
                 int* __restrict__ esrc, float* __restrict__ eatt, int e) {
    for (int i = blockIdx.x * 256 + threadIdx.x; i < e; i += gridDim.x * 256) {
        int p = atomicAdd(cursor + dst[i], 1);
        esrc[p] = src[i];
        eatt[p] = eattr[i];
    }
}

// ---------- fused 4-way linear: q | s | kv-interleaved = X @ {Wq,Ws,Wk,Wv} + b ----------
// task index cc in [0,4C): [0,C)->q col cc ; [C,2C)->s col cc-C ;
// [2C,4C)->kv element cc-2C  (even = k col (cc-2C)/2, odd = v col) -> coalesced stores
template<int FIN, int C>
__global__ __launch_bounds__(256)
void linear4_kernel(const float* __restrict__ X,
                    const float* __restrict__ Wq, const float* __restrict__ bq,
                    const float* __restrict__ Wk, const float* __restrict__ bk,
                    const float* __restrict__ Wv, const float* __restrict__ bv,
                    const float* __restrict__ Ws, const float* __restrict__ bs,
                    float* __restrict__ q, float* __restrict__ kv,
                    float* __restrict__ s, int n)
{
    constexpr int FOURC = 4 * C;
    __shared__ float wsh[FIN * FOURC];
    __shared__ float bsh[FOURC];
    for (int i = threadIdx.x; i < FIN * C; i += 256) {
        int f = i / C, c = i - (i / C) * C;
        wsh[f * FOURC + c]                 = Wq[i];
        wsh[f * FOURC + C + c]             = Ws[i];
        wsh[f * FOURC + 2 * C + 2 * c]     = Wk[i];
        wsh[f * FOURC + 2 * C + 2 * c + 1] = Wv[i];
    }
    for (int i = threadIdx.x; i < C; i += 256) {
        bsh[i] = bq[i]; bsh[C + i] = bs[i];
        bsh[2 * C + 2 * i] = bk[i]; bsh[2 * C + 2 * i + 1] = bv[i];
    }
    __syncthreads();
    const int total = n * FOURC;
    for (int idx = blockIdx.x * 256 + threadIdx.x; idx < total; idx += gridDim.x * 256) {
        int row = idx / FOURC;
        int cc  = idx - row * FOURC;
        const float* xr = X + (size_t)row * FIN;
        float acc = bsh[cc];
        #pragma unroll
        for (int f = 0; f < FIN; ++f) acc = fmaf(xr[f], wsh[f * FOURC + cc], acc);
        if (cc < C)          q[(size_t)row * C + cc] = acc;
        else if (cc < 2 * C) s[(size_t)row * C + cc - C] = acc;
        else                 kv[(size_t)row * 2 * C + cc - 2 * C] = acc;
    }
}

// ---------- fused conv: per-node softmax (no max shift) + aggregation + skip + ELU ----------
template<int C>
__global__ __launch_bounds__(256)
void conv_fused_kernel(const int* __restrict__ rowptr, const int* __restrict__ esrc,
                       const float* __restrict__ eatt,
                       const float* __restrict__ q, const float2* __restrict__ kv,
                       const float* __restrict__ sres,
                       const float* __restrict__ We, const float* __restrict__ be,
                       float* __restrict__ h, float scale, int n)
{
    constexpr int EPI    = 64 / C;             // edge slots per wave (1 or 2)
    constexpr int UNROLL = (C == 64) ? 4 : 2;  // independent edges in flight per slot
    constexpr int LOGC   = (C == 64) ? 6 : 5;
    const int wave = threadIdx.x >> 6;
    const int lane = threadIdx.x & 63;
    const int c    = lane & (C - 1);
    const int slot = lane >> LOGC;
    const int node = blockIdx.x * 4 + wave;
    if (node >= n) return;

    const float wec = We[c], bec = be[c];
    const float qc  = q[(size_t)node * C + c];
    const int r0 = rowptr[node], r1 = rowptr[node + 1];

    float ssum = 0.f, acc = 0.f;
    int j = r0 + slot;
    for (; j + (UNROLL - 1) * EPI < r1; j += UNROLL * EPI) {
        int sN[UNROLL]; float ea[UNROLL]; float2 f[UNROLL];
        #pragma unroll
        for (int u = 0; u < UNROLL; ++u) {
            sN[u] = esrc[j + u * EPI];
            ea[u] = eatt[j + u * EPI];
        }
        #pragma unroll
        for (int u = 0; u < UNROLL; ++u) f[u] = kv[(size_t)sN[u] * C + c];
        #pragma unroll
        for (int u = 0; u < UNROLL; ++u) {
            float ec = fmaf(ea[u], wec, bec);
            float p = qc * (f[u].x + ec);
            #pragma unroll
            for (int off = C >> 1; off > 0; off >>= 1) p += __shfl_xor(p, off, C);
            float w = __expf(p * scale);
            ssum += w;
            acc = fmaf(w, f[u].y + ec, acc);
        }
    }
    for (; j < r1; j += EPI) {
        int sN = esrc[j]; float ea = eatt[j];
        float2 f = kv[(size_t)sN * C + c];
        float ec = fmaf(ea, wec, bec);
        float p = qc * (f.x + ec);
        #pragma unroll
        for (int off = C >> 1; off > 0; off >>= 1) p += __shfl_xor(p, off, C);
        float w = __expf(p * scale);
        ssum += w;
        acc = fmaf(w, f.y + ec, acc);
    }

    if constexpr (EPI == 2) {   // merge the two slot streams (plain sums — no max)
        ssum += __shfl_xor(ssum, 32);
        acc  += __shfl_xor(acc, 32);
    }

    if (slot == 0) {
        float outv = acc / (ssum + 1e-16f);
        float hv = outv + sres[(size_t)node * C + c];
        h[(size_t)node * C + c] = (hv > 0.f) ? hv : expm1f(hv);
    }
}

// ---------- single linear (+ optional ELU) ----------
template<int FIN, int COUT, bool ELU>
__global__ __launch_bounds__(256)
void linear1_kernel(const float* __restrict__ X, const float* __restrict__ W,
                    const float* __restrict__ b, float* __restrict__ out, int n)
{
    __shared__ float wsh[FIN * COUT];
    __shared__ float bsh[COUT];
    for (int i = threadIdx.x; i < FIN * COUT; i += 256) wsh[i] = W[i];
    for (int i = threadIdx.x; i < COUT; i += 256) bsh[i] = b[i];
    __syncthreads();
    const int total = n * COUT;
    for (int idx = blockIdx.x * 256 + threadIdx.x; idx < total; idx += gridDim.x * 256) {
        int row = idx / COUT;
        int c   = idx - row * COUT;
        const float* xr = X + (size_t)row * FIN;
        float acc = bsh[c];
        #pragma unroll
        for (int f = 0; f < FIN; ++f) acc = fmaf(xr[f], wsh[f * COUT + c], acc);
        if (ELU) acc = (acc > 0.f) ? acc : expm1f(acc);
        out[(size_t)row * COUT + c] = acc;
    }
}

// ---------- fc2 + log_softmax ----------
#define H1_DIM 128
#define NC_DIM 10
__global__ __launch_bounds__(256)
void head_kernel(const float* __restrict__ Hf, const float* __restrict__ W,
                 const float* __restrict__ b, float* __restrict__ out, int n)
{
    __shared__ float wsh[H1_DIM * NC_DIM];
    __shared__ float bsh[NC_DIM];
    for (int i = threadIdx.x; i < H1_DIM * NC_DIM; i += 256) wsh[i] = W[i];
    for (int i = threadIdx.x; i < NC_DIM; i += 256) bsh[i] = b[i];
    __syncthreads();
    for (int row = blockIdx.x * 256 + threadIdx.x; row < n; row += gridDim.x * 256) {
        const float* hr = Hf + (size_t)row * H1_DIM;
        float logit[NC_DIM];
        #pragma unroll
        for (int c = 0; c < NC_DIM; ++c) logit[c] = bsh[c];
        for (int f = 0; f < H1_DIM; ++f) {
            float xv = hr[f];
            #pragma unroll
            for (int c = 0; c < NC_DIM; ++c) logit[c] = fmaf(xv, wsh[f * NC_DIM + c], logit[c]);
        }
        float m = logit[0];
        #pragma unroll
        for (int c = 1; c < NC_DIM; ++c) m = fmaxf(m, logit[c]);
        float sum = 0.f;
        #pragma unroll
        for (int c = 0; c < NC_DIM; ++c) sum += __expf(logit[c] - m);
        float lse = m + logf(sum);
        #pragma unroll
        for (int c = 0; c < NC_DIM; ++c) out[(size_t)row * NC_DIM + c] = logit[c] - lse;
    }
}

extern "C" void kernel_launch(void* const* d_in, const int* in_sizes, int n_in,
                              void* d_out, int out_size, void* d_ws, size_t ws_size,
                              hipStream_t stream) {
    const float* x   = (const float*)d_in[0];
    const int*   ei  = (const int*)d_in[1];
    const float* ea  = (const float*)d_in[2];
    const float *Wq1 = (const float*)d_in[3],  *bq1 = (const float*)d_in[4];
    const float *Wk1 = (const float*)d_in[5],  *bk1 = (const float*)d_in[6];
    const float *Wv1 = (const float*)d_in[7],  *bv1 = (const float*)d_in[8];
    const float *We1 = (const float*)d_in[9],  *be1 = (const float*)d_in[10];
    const float *Ws1 = (const float*)d_in[11], *bs1 = (const float*)d_in[12];
    const float *Wq2 = (const float*)d_in[13], *bq2 = (const float*)d_in[14];
    const float *Wk2 = (const float*)d_in[15], *bk2 = (const float*)d_in[16];
    const float *Wv2 = (const float*)d_in[17], *bv2 = (const float*)d_in[18];
    const float *We2 = (const float*)d_in[19], *be2 = (const float*)d_in[20];
    const float *Ws2 = (const float*)d_in[21], *bs2 = (const float*)d_in[22];
    const float *Wf1 = (const float*)d_in[23], *bf1 = (const float*)d_in[24];
    const float *Wf2 = (const float*)d_in[25], *bf2 = (const float*)d_in[26];

    const int N = in_sizes[0] / 64;   // 100000
    const int E = in_sizes[2];        // 1600000
    const int* src = ei;              // edge_index[0]
    const int* dst = ei + E;          // edge_index[1]

    float* wsf = (float*)d_ws;
    const size_t N64 = (size_t)N * 64;
    float* q   = wsf;                        // N*64
    float* kv  = q + N64;                    // N*128 (channel-interleaved k|v)
    float* s   = kv + (size_t)N * 128;       // N*64 (skip proj)
    float* h1  = s + N64;                    // N*32
    float* h2  = h1 + (size_t)N * 32;        // N*64
    int* deg     = (int*)(h2 + N64);         // N
    int* rowptr  = deg + N;                  // N+1
    int* cursor  = rowptr + N + 1;           // N
    int* bsum    = cursor + N;               // SCAN_NB
    int* boff    = bsum + SCAN_NB;           // SCAN_NB
    int* esrc    = boff + SCAN_NB;           // E
    float* eatt  = (float*)(esrc + E);       // E
    float* hfc   = wsf;                      // N*128 (reuses dead q after conv2)

    float* out = (float*)d_out;

    // ---- CSR build ----
    hipMemsetAsync(deg, 0, (size_t)N * 4, stream);
    count_deg_kernel<<<2048, 256, 0, stream>>>(dst, deg, E);
    blocksum_kernel<<<SCAN_NB, 256, 0, stream>>>(deg, bsum, N);
    scanb_kernel<<<1, 256, 0, stream>>>(bsum, boff, rowptr + N, SCAN_NB);
    writeptr_kernel<<<SCAN_NB, 256, 0, stream>>>(deg, boff, rowptr, cursor, N);
    fill_kernel<<<4096, 256, 0, stream>>>(src, dst, ea, cursor, esrc, eatt, E);

    const int convGrid = (N + 3) / 4;

    // ---- layer 1 (C=32) ----
    linear4_kernel<64, 32><<<2048, 256, 0, stream>>>(
        x, Wq1, bq1, Wk1, bk1, Wv1, bv1, Ws1, bs1, q, kv, s, N);
    conv_fused_kernel<32><<<convGrid, 256, 0, stream>>>(
        rowptr, esrc, eatt, q, (const float2*)kv, s, We1, be1, h1,
        0.17677669529663687f, N);

    // ---- layer 2 (C=64) ----
    linear4_kernel<32, 64><<<2048, 256, 0, stream>>>(
        h1, Wq2, bq2, Wk2, bk2, Wv2, bv2, Ws2, bs2, q, kv, s, N);
    conv_fused_kernel<64><<<convGrid, 256, 0, stream>>>(
        rowptr, esrc, eatt, q, (const float2*)kv, s, We2, be2, h2, 0.125f, N);

    // ---- MLP head ----
    linear1_kernel<64, 128, true><<<2048, 256, 0, stream>>>(h2, Wf1, bf1, hfc, N);
    head_kernel<<<512, 256, 0, stream>>>(hfc, Wf2, bf2, out, N);
}

// Round 5
// 628.344 us; speedup vs baseline: 2.3180x; 1.1562x over previous
//
#include <hip/hip_runtime.h>
#include <math.h>

// TransformerConvNet: 2x TransformerConv(heads=1) + ELU + MLP head + log_softmax
// N=100000 nodes, E=1600000 edges, F_IN=64, C1=32, C2=64, H1=128, NC=10
//
// R5: CSR build without fill-atomics — count pass records per-edge rank
// (atomicAdd return value); fill computes p = rowptr[dst] + rank and does a
// single packed int2 scatter. Cursor array eliminated.

#define SCAN_NB 256

// ---------- CSR build ----------
// counts degree AND records each edge's rank within its dst segment
__global__ __launch_bounds__(256)
void count_rank_kernel(const int* __restrict__ dst, int* __restrict__ deg,
                       int* __restrict__ rank, int e) {
    for (int i = blockIdx.x * 256 + threadIdx.x; i < e; i += gridDim.x * 256)
        rank[i] = atomicAdd(deg + dst[i], 1);
}

__global__ __launch_bounds__(256)
void blocksum_kernel(const int* __restrict__ deg, int* __restrict__ bsum, int n) {
    __shared__ int ls[256];
    const int chunk = (n + gridDim.x - 1) / gridDim.x;
    const int b0 = blockIdx.x * chunk;
    const int b1 = (b0 + chunk < n) ? b0 + chunk : n;
    int s = 0;
    for (int i = b0 + threadIdx.x; i < b1; i += 256) s += deg[i];
    ls[threadIdx.x] = s;
    __syncthreads();
    for (int off = 128; off > 0; off >>= 1) {
        if (threadIdx.x < off) ls[threadIdx.x] += ls[threadIdx.x + off];
        __syncthreads();
    }
    if (threadIdx.x == 0) bsum[blockIdx.x] = ls[0];
}

__global__ __launch_bounds__(256)
void scanb_kernel(const int* __restrict__ bsum, int* __restrict__ boff,
                  int* __restrict__ total, int nb) {
    __shared__ int ls[256];
    const int t = threadIdx.x;
    int v = (t < nb) ? bsum[t] : 0;
    ls[t] = v;
    __syncthreads();
    for (int off = 1; off < 256; off <<= 1) {
        int u = (t >= off) ? ls[t - off] : 0;
        __syncthreads();
        ls[t] += u;
        __syncthreads();
    }
    if (t < nb) boff[t] = ls[t] - v;
    if (t == 255) *total = ls[255];
}

__global__ __launch_bounds__(256)
void writeptr_kernel(const int* __restrict__ deg, const int* __restrict__ boff,
                     int* __restrict__ rowptr, int n) {
    __shared__ int ls[256];
    const int chunk = (n + gridDim.x - 1) / gridDim.x;
    const int b0 = blockIdx.x * chunk;
    const int b1 = (b0 + chunk < n) ? b0 + chunk : n;
    const int tchunk = (chunk + 255) / 256;
    const int t0 = b0 + threadIdx.x * tchunk;
    const int t1 = (t0 + tchunk < b1) ? t0 + tchunk : b1;
    int s = 0;
    for (int i = t0; i < t1; ++i) s += deg[i];
    ls[threadIdx.x] = s;
    __syncthreads();
    for (int off = 1; off < 256; off <<= 1) {
        int u = (threadIdx.x >= off) ? ls[threadIdx.x - off] : 0;
        __syncthreads();
        ls[threadIdx.x] += u;
        __syncthreads();
    }
    int run = boff[blockIdx.x] + ls[threadIdx.x] - s;
    for (int i = t0; i < t1; ++i) { rowptr[i] = run; run += deg[i]; }
}

// scatter packed {src, eattr} to CSR position rowptr[dst]+rank — no atomics
__global__ __launch_bounds__(256)
void fill_pack_kernel(const int* __restrict__ src, const int* __restrict__ dst,
                      const float* __restrict__ eattr,
                      const int* __restrict__ rowptr, const int* __restrict__ rank,
                      int2* __restrict__ ecsr, int e) {
    for (int i = blockIdx.x * 256 + threadIdx.x; i < e; i += gridDim.x * 256) {
        int p = rowptr[dst[i]] + rank[i];
        ecsr[p] = make_int2(src[i], __float_as_int(eattr[i]));
    }
}

// ---------- fused 4-way linear: q | s | kv-interleaved = X @ {Wq,Ws,Wk,Wv} + b ----------
template<int FIN, int C>
__global__ __launch_bounds__(256)
void linear4_kernel(const float* __restrict__ X,
                    const float* __restrict__ Wq, const float* __restrict__ bq,
                    const float* __restrict__ Wk, const float* __restrict__ bk,
                    const float* __restrict__ Wv, const float* __restrict__ bv,
                    const float* __restrict__ Ws, const float* __restrict__ bs,
                    float* __restrict__ q, float* __restrict__ kv,
                    float* __restrict__ s, int n)
{
    constexpr int FOURC = 4 * C;
    __shared__ float wsh[FIN * FOURC];
    __shared__ float bsh[FOURC];
    for (int i = threadIdx.x; i < FIN * C; i += 256) {
        int f = i / C, c = i - (i / C) * C;
        wsh[f * FOURC + c]                 = Wq[i];
        wsh[f * FOURC + C + c]             = Ws[i];
        wsh[f * FOURC + 2 * C + 2 * c]     = Wk[i];
        wsh[f * FOURC + 2 * C + 2 * c + 1] = Wv[i];
    }
    for (int i = threadIdx.x; i < C; i += 256) {
        bsh[i] = bq[i]; bsh[C + i] = bs[i];
        bsh[2 * C + 2 * i] = bk[i]; bsh[2 * C + 2 * i + 1] = bv[i];
    }
    __syncthreads();
    const int total = n * FOURC;
    for (int idx = blockIdx.x * 256 + threadIdx.x; idx < total; idx += gridDim.x * 256) {
        int row = idx / FOURC;
        int cc  = idx - row * FOURC;
        const float* xr = X + (size_t)row * FIN;
        float acc = bsh[cc];
        #pragma unroll
        for (int f = 0; f < FIN; ++f) acc = fmaf(xr[f], wsh[f * FOURC + cc], acc);
        if (cc < C)          q[(size_t)row * C + cc] = acc;
        else if (cc < 2 * C) s[(size_t)row * C + cc - C] = acc;
        else                 kv[(size_t)row * 2 * C + cc - 2 * C] = acc;
    }
}

// ---------- fused conv: per-node softmax (no max shift) + aggregation + skip + ELU ----------
template<int C>
__global__ __launch_bounds__(256)
void conv_fused_kernel(const int* __restrict__ rowptr, const int2* __restrict__ ecsr,
                       const float* __restrict__ q, const float2* __restrict__ kv,
                       const float* __restrict__ sres,
                       const float* __restrict__ We, const float* __restrict__ be,
                       float* __restrict__ h, float scale, int n)
{
    constexpr int EPI    = 64 / C;             // edge slots per wave (1 or 2)
    constexpr int UNROLL = (C == 64) ? 4 : 2;  // independent edges in flight per slot
    constexpr int LOGC   = (C == 64) ? 6 : 5;
    const int wave = threadIdx.x >> 6;
    const int lane = threadIdx.x & 63;
    const int c    = lane & (C - 1);
    const int slot = lane >> LOGC;
    const int node = blockIdx.x * 4 + wave;
    if (node >= n) return;

    const float wec = We[c], bec = be[c];
    const float qc  = q[(size_t)node * C + c];
    const int r0 = rowptr[node], r1 = rowptr[node + 1];

    float ssum = 0.f, acc = 0.f;
    int j = r0 + slot;
    for (; j + (UNROLL - 1) * EPI < r1; j += UNROLL * EPI) {
        int2 epk[UNROLL]; float2 f[UNROLL];
        #pragma unroll
        for (int u = 0; u < UNROLL; ++u) epk[u] = ecsr[j + u * EPI];
        #pragma unroll
        for (int u = 0; u < UNROLL; ++u) f[u] = kv[(size_t)epk[u].x * C + c];
        #pragma unroll
        for (int u = 0; u < UNROLL; ++u) {
            float ec = fmaf(__int_as_float(epk[u].y), wec, bec);
            float p = qc * (f[u].x + ec);
            #pragma unroll
            for (int off = C >> 1; off > 0; off >>= 1) p += __shfl_xor(p, off, C);
            float w = __expf(p * scale);
            ssum += w;
            acc = fmaf(w, f[u].y + ec, acc);
        }
    }
    for (; j < r1; j += EPI) {
        int2 epk = ecsr[j];
        float2 f = kv[(size_t)epk.x * C + c];
        float ec = fmaf(__int_as_float(epk.y), wec, bec);
        float p = qc * (f.x + ec);
        #pragma unroll
        for (int off = C >> 1; off > 0; off >>= 1) p += __shfl_xor(p, off, C);
        float w = __expf(p * scale);
        ssum += w;
        acc = fmaf(w, f.y + ec, acc);
    }

    if constexpr (EPI == 2) {   // merge the two slot streams (plain sums — no max)
        ssum += __shfl_xor(ssum, 32);
        acc  += __shfl_xor(acc, 32);
    }

    if (slot == 0) {
        float outv = acc / (ssum + 1e-16f);
        float hv = outv + sres[(size_t)node * C + c];
        h[(size_t)node * C + c] = (hv > 0.f) ? hv : expm1f(hv);
    }
}

// ---------- single linear (+ optional ELU) ----------
template<int FIN, int COUT, bool ELU>
__global__ __launch_bounds__(256)
void linear1_kernel(const float* __restrict__ X, const float* __restrict__ W,
                    const float* __restrict__ b, float* __restrict__ out, int n)
{
    __shared__ float wsh[FIN * COUT];
    __shared__ float bsh[COUT];
    for (int i = threadIdx.x; i < FIN * COUT; i += 256) wsh[i] = W[i];
    for (int i = threadIdx.x; i < COUT; i += 256) bsh[i] = b[i];
    __syncthreads();
    const int total = n * COUT;
    for (int idx = blockIdx.x * 256 + threadIdx.x; idx < total; idx += gridDim.x * 256) {
        int row = idx / COUT;
        int c   = idx - row * COUT;
        const float* xr = X + (size_t)row * FIN;
        float acc = bsh[c];
        #pragma unroll
        for (int f = 0; f < FIN; ++f) acc = fmaf(xr[f], wsh[f * COUT + c], acc);
        if (ELU) acc = (acc > 0.f) ? acc : expm1f(acc);
        out[(size_t)row * COUT + c] = acc;
    }
}

// ---------- fc2 + log_softmax ----------
#define H1_DIM 128
#define NC_DIM 10
__global__ __launch_bounds__(256)
void head_kernel(const float* __restrict__ Hf, const float* __restrict__ W,
                 const float* __restrict__ b, float* __restrict__ out, int n)
{
    __shared__ float wsh[H1_DIM * NC_DIM];
    __shared__ float bsh[NC_DIM];
    for (int i = threadIdx.x; i < H1_DIM * NC_DIM; i += 256) wsh[i] = W[i];
    for (int i = threadIdx.x; i < NC_DIM; i += 256) bsh[i] = b[i];
    __syncthreads();
    for (int row = blockIdx.x * 256 + threadIdx.x; row < n; row += gridDim.x * 256) {
        const float* hr = Hf + (size_t)row * H1_DIM;
        float logit[NC_DIM];
        #pragma unroll
        for (int c = 0; c < NC_DIM; ++c) logit[c] = bsh[c];
        for (int f = 0; f < H1_DIM; ++f) {
            float xv = hr[f];
            #pragma unroll
            for (int c = 0; c < NC_DIM; ++c) logit[c] = fmaf(xv, wsh[f * NC_DIM + c], logit[c]);
        }
        float m = logit[0];
        #pragma unroll
        for (int c = 1; c < NC_DIM; ++c) m = fmaxf(m, logit[c]);
        float sum = 0.f;
        #pragma unroll
        for (int c = 0; c < NC_DIM; ++c) sum += __expf(logit[c] - m);
        float lse = m + logf(sum);
        #pragma unroll
        for (int c = 0; c < NC_DIM; ++c) out[(size_t)row * NC_DIM + c] = logit[c] - lse;
    }
}

extern "C" void kernel_launch(void* const* d_in, const int* in_sizes, int n_in,
                              void* d_out, int out_size, void* d_ws, size_t ws_size,
                              hipStream_t stream) {
    const float* x   = (const float*)d_in[0];
    const int*   ei  = (const int*)d_in[1];
    const float* ea  = (const float*)d_in[2];
    const float *Wq1 = (const float*)d_in[3],  *bq1 = (const float*)d_in[4];
    const float *Wk1 = (const float*)d_in[5],  *bk1 = (const float*)d_in[6];
    const float *Wv1 = (const float*)d_in[7],  *bv1 = (const float*)d_in[8];
    const float *We1 = (const float*)d_in[9],  *be1 = (const float*)d_in[10];
    const float *Ws1 = (const float*)d_in[11], *bs1 = (const float*)d_in[12];
    const float *Wq2 = (const float*)d_in[13], *bq2 = (const float*)d_in[14];
    const float *Wk2 = (const float*)d_in[15], *bk2 = (const float*)d_in[16];
    const float *Wv2 = (const float*)d_in[17], *bv2 = (const float*)d_in[18];
    const float *We2 = (const float*)d_in[19], *be2 = (const float*)d_in[20];
    const float *Ws2 = (const float*)d_in[21], *bs2 = (const float*)d_in[22];
    const float *Wf1 = (const float*)d_in[23], *bf1 = (const float*)d_in[24];
    const float *Wf2 = (const float*)d_in[25], *bf2 = (const float*)d_in[26];

    const int N = in_sizes[0] / 64;   // 100000
    const int E = in_sizes[2];        // 1600000
    const int* src = ei;              // edge_index[0]
    const int* dst = ei + E;          // edge_index[1]

    float* wsf = (float*)d_ws;
    const size_t N64 = (size_t)N * 64;
    float* q   = wsf;                        // N*64
    float* kv  = q + N64;                    // N*128 (channel-interleaved k|v)
    float* s   = kv + (size_t)N * 128;       // N*64 (skip proj)
    float* h1  = s + N64;                    // N*32
    float* h2  = h1 + (size_t)N * 32;        // N*64
    int* deg     = (int*)(h2 + N64);         // N
    int* rowptr  = deg + N;                  // N+1
    int* bsum    = rowptr + N + 1;           // SCAN_NB
    int* boff    = bsum + SCAN_NB;           // SCAN_NB
    int* rank    = boff + SCAN_NB;           // E
    int2* ecsr   = (int2*)(rank + E);        // E (packed {src, eattr})
    float* hfc   = wsf;                      // N*128 (reuses dead q after conv2)

    float* out = (float*)d_out;

    // ---- CSR build ----
    hipMemsetAsync(deg, 0, (size_t)N * 4, stream);
    count_rank_kernel<<<2048, 256, 0, stream>>>(dst, deg, rank, E);
    blocksum_kernel<<<SCAN_NB, 256, 0, stream>>>(deg, bsum, N);
    scanb_kernel<<<1, 256, 0, stream>>>(bsum, boff, rowptr + N, SCAN_NB);
    writeptr_kernel<<<SCAN_NB, 256, 0, stream>>>(deg, boff, rowptr, N);
    fill_pack_kernel<<<4096, 256, 0, stream>>>(src, dst, ea, rowptr, rank, ecsr, E);

    const int convGrid = (N + 3) / 4;

    // ---- layer 1 (C=32) ----
    linear4_kernel<64, 32><<<2048, 256, 0, stream>>>(
        x, Wq1, bq1, Wk1, bk1, Wv1, bv1, Ws1, bs1, q, kv, s, N);
    conv_fused_kernel<32><<<convGrid, 256, 0, stream>>>(
        rowptr, ecsr, q, (const float2*)kv, s, We1, be1, h1,
        0.17677669529663687f, N);

    // ---- layer 2 (C=64) ----
    linear4_kernel<32, 64><<<2048, 256, 0, stream>>>(
        h1, Wq2, bq2, Wk2, bk2, Wv2, bv2, Ws2, bs2, q, kv, s, N);
    conv_fused_kernel<64><<<convGrid, 256, 0, stream>>>(
        rowptr, ecsr, q, (const float2*)kv, s, We2, be2, h2, 0.125f, N);

    // ---- MLP head ----
    linear1_kernel<64, 128, true><<<2048, 256, 0, stream>>>(h2, Wf1, bf1, hfc, N);
    head_kernel<<<512, 256, 0, stream>>>(hfc, Wf2, bf2, out, N);
}

// Round 7
// 604.858 us; speedup vs baseline: 2.4081x; 1.0388x over previous
//
#include <hip/hip_runtime.h>
#include <hip/hip_fp16.h>
#include <math.h>

// TransformerConvNet: 2x TransformerConv(heads=1) + ELU + MLP head + log_softmax
// N=100000 nodes, E=1600000 edges, F_IN=64, C1=32, C2=64, H1=128, NC=10
//
// R6 (resubmit after infra failure): kv stored as packed __half2{k,v} per
// channel — halves the random-gather traffic in conv_fused (the 406 MB FETCH
// bottleneck) and doubles effective L2 coverage of the kv working set.

#define SCAN_NB 256

// ---------- CSR build ----------
__global__ __launch_bounds__(256)
void count_rank_kernel(const int* __restrict__ dst, int* __restrict__ deg,
                       int* __restrict__ rank, int e) {
    for (int i = blockIdx.x * 256 + threadIdx.x; i < e; i += gridDim.x * 256)
        rank[i] = atomicAdd(deg + dst[i], 1);
}

__global__ __launch_bounds__(256)
void blocksum_kernel(const int* __restrict__ deg, int* __restrict__ bsum, int n) {
    __shared__ int ls[256];
    const int chunk = (n + gridDim.x - 1) / gridDim.x;
    const int b0 = blockIdx.x * chunk;
    const int b1 = (b0 + chunk < n) ? b0 + chunk : n;
    int s = 0;
    for (int i = b0 + threadIdx.x; i < b1; i += 256) s += deg[i];
    ls[threadIdx.x] = s;
    __syncthreads();
    for (int off = 128; off > 0; off >>= 1) {
        if (threadIdx.x < off) ls[threadIdx.x] += ls[threadIdx.x + off];
        __syncthreads();
    }
    if (threadIdx.x == 0) bsum[blockIdx.x] = ls[0];
}

__global__ __launch_bounds__(256)
void scanb_kernel(const int* __restrict__ bsum, int* __restrict__ boff,
                  int* __restrict__ total, int nb) {
    __shared__ int ls[256];
    const int t = threadIdx.x;
    int v = (t < nb) ? bsum[t] : 0;
    ls[t] = v;
    __syncthreads();
    for (int off = 1; off < 256; off <<= 1) {
        int u = (t >= off) ? ls[t - off] : 0;
        __syncthreads();
        ls[t] += u;
        __syncthreads();
    }
    if (t < nb) boff[t] = ls[t] - v;
    if (t == 255) *total = ls[255];
}

__global__ __launch_bounds__(256)
void writeptr_kernel(const int* __restrict__ deg, const int* __restrict__ boff,
                     int* __restrict__ rowptr, int n) {
    __shared__ int ls[256];
    const int chunk = (n + gridDim.x - 1) / gridDim.x;
    const int b0 = blockIdx.x * chunk;
    const int b1 = (b0 + chunk < n) ? b0 + chunk : n;
    const int tchunk = (chunk + 255) / 256;
    const int t0 = b0 + threadIdx.x * tchunk;
    const int t1 = (t0 + tchunk < b1) ? t0 + tchunk : b1;
    int s = 0;
    for (int i = t0; i < t1; ++i) s += deg[i];
    ls[threadIdx.x] = s;
    __syncthreads();
    for (int off = 1; off < 256; off <<= 1) {
        int u = (threadIdx.x >= off) ? ls[threadIdx.x - off] : 0;
        __syncthreads();
        ls[threadIdx.x] += u;
        __syncthreads();
    }
    int run = boff[blockIdx.x] + ls[threadIdx.x] - s;
    for (int i = t0; i < t1; ++i) { rowptr[i] = run; run += deg[i]; }
}

__global__ __launch_bounds__(256)
void fill_pack_kernel(const int* __restrict__ src, const int* __restrict__ dst,
                      const float* __restrict__ eattr,
                      const int* __restrict__ rowptr, const int* __restrict__ rank,
                      int2* __restrict__ ecsr, int e) {
    for (int i = blockIdx.x * 256 + threadIdx.x; i < e; i += gridDim.x * 256) {
        int p = rowptr[dst[i]] + rank[i];
        ecsr[p] = make_int2(src[i], __float_as_int(eattr[i]));
    }
}

// ---------- fused 4-way linear: q | s (fp32) + kv packed half2 ----------
// tasks per row: [0,C) -> q col ; [C,2C) -> s col ; [2C,3C) -> {k,v} pair col
template<int FIN, int C>
__global__ __launch_bounds__(256)
void linear4_kernel(const float* __restrict__ X,
                    const float* __restrict__ Wq, const float* __restrict__ bq,
                    const float* __restrict__ Wk, const float* __restrict__ bk,
                    const float* __restrict__ Wv, const float* __restrict__ bv,
                    const float* __restrict__ Ws, const float* __restrict__ bs,
                    float* __restrict__ q, __half2* __restrict__ kv,
                    float* __restrict__ s, int n)
{
    constexpr int FOURC = 4 * C;
    constexpr int TPR   = 3 * C;   // tasks per row
    __shared__ float wsh[FIN * FOURC];  // layout: q [0,C) | s [C,2C) | k [2C,3C) | v [3C,4C)
    __shared__ float bsh[FOURC];
    for (int i = threadIdx.x; i < FIN * C; i += 256) {
        int f = i / C, c = i - (i / C) * C;
        wsh[f * FOURC + c]         = Wq[i];
        wsh[f * FOURC + C + c]     = Ws[i];
        wsh[f * FOURC + 2 * C + c] = Wk[i];
        wsh[f * FOURC + 3 * C + c] = Wv[i];
    }
    for (int i = threadIdx.x; i < C; i += 256) {
        bsh[i] = bq[i]; bsh[C + i] = bs[i];
        bsh[2 * C + i] = bk[i]; bsh[3 * C + i] = bv[i];
    }
    __syncthreads();
    const int total = n * TPR;
    for (int idx = blockIdx.x * 256 + threadIdx.x; idx < total; idx += gridDim.x * 256) {
        int row = idx / TPR;
        int cc  = idx - row * TPR;
        const float* xr = X + (size_t)row * FIN;
        if (cc < 2 * C) {
            float acc = bsh[cc];
            #pragma unroll
            for (int f = 0; f < FIN; ++f) acc = fmaf(xr[f], wsh[f * FOURC + cc], acc);
            if (cc < C) q[(size_t)row * C + cc] = acc;
            else        s[(size_t)row * C + cc - C] = acc;
        } else {
            int c = cc - 2 * C;
            float ak = bsh[2 * C + c], av = bsh[3 * C + c];
            #pragma unroll
            for (int f = 0; f < FIN; ++f) {
                float xv = xr[f];
                ak = fmaf(xv, wsh[f * FOURC + 2 * C + c], ak);
                av = fmaf(xv, wsh[f * FOURC + 3 * C + c], av);
            }
            kv[(size_t)row * C + c] = __floats2half2_rn(ak, av);
        }
    }
}

// ---------- fused conv: per-node softmax (no max shift) + aggregation + skip + ELU ----------
template<int C>
__global__ __launch_bounds__(256)
void conv_fused_kernel(const int* __restrict__ rowptr, const int2* __restrict__ ecsr,
                       const float* __restrict__ q, const __half2* __restrict__ kv,
                       const float* __restrict__ sres,
                       const float* __restrict__ We, const float* __restrict__ be,
                       float* __restrict__ h, float scale, int n)
{
    constexpr int EPI    = 64 / C;             // edge slots per wave (1 or 2)
    constexpr int UNROLL = (C == 64) ? 4 : 2;  // independent edges in flight per slot
    constexpr int LOGC   = (C == 64) ? 6 : 5;
    const int wave = threadIdx.x >> 6;
    const int lane = threadIdx.x & 63;
    const int c    = lane & (C - 1);
    const int slot = lane >> LOGC;
    const int node = blockIdx.x * 4 + wave;
    if (node >= n) return;

    const float wec = We[c], bec = be[c];
    const float qc  = q[(size_t)node * C + c];
    const int r0 = rowptr[node], r1 = rowptr[node + 1];

    float ssum = 0.f, acc = 0.f;
    int j = r0 + slot;
    for (; j + (UNROLL - 1) * EPI < r1; j += UNROLL * EPI) {
        int2 epk[UNROLL]; __half2 f[UNROLL];
        #pragma unroll
        for (int u = 0; u < UNROLL; ++u) epk[u] = ecsr[j + u * EPI];
        #pragma unroll
        for (int u = 0; u < UNROLL; ++u) f[u] = kv[(size_t)epk[u].x * C + c];
        #pragma unroll
        for (int u = 0; u < UNROLL; ++u) {
            float2 fv = __half22float2(f[u]);
            float ec = fmaf(__int_as_float(epk[u].y), wec, bec);
            float p = qc * (fv.x + ec);
            #pragma unroll
            for (int off = C >> 1; off > 0; off >>= 1) p += __shfl_xor(p, off, C);
            float w = __expf(p * scale);
            ssum += w;
            acc = fmaf(w, fv.y + ec, acc);
        }
    }
    for (; j < r1; j += EPI) {
        int2 epk = ecsr[j];
        float2 fv = __half22float2(kv[(size_t)epk.x * C + c]);
        float ec = fmaf(__int_as_float(epk.y), wec, bec);
        float p = qc * (fv.x + ec);
        #pragma unroll
        for (int off = C >> 1; off > 0; off >>= 1) p += __shfl_xor(p, off, C);
        float w = __expf(p * scale);
        ssum += w;
        acc = fmaf(w, fv.y + ec, acc);
    }

    if constexpr (EPI == 2) {   // merge the two slot streams (plain sums — no max)
        ssum += __shfl_xor(ssum, 32);
        acc  += __shfl_xor(acc, 32);
    }

    if (slot == 0) {
        float outv = acc / (ssum + 1e-16f);
        float hv = outv + sres[(size_t)node * C + c];
        h[(size_t)node * C + c] = (hv > 0.f) ? hv : expm1f(hv);
    }
}

// ---------- single linear (+ optional ELU) ----------
template<int FIN, int COUT, bool ELU>
__global__ __launch_bounds__(256)
void linear1_kernel(const float* __restrict__ X, const float* __restrict__ W,
                    const float* __restrict__ b, float* __restrict__ out, int n)
{
    __shared__ float wsh[FIN * COUT];
    __shared__ float bsh[COUT];
    for (int i = threadIdx.x; i < FIN * COUT; i += 256) wsh[i] = W[i];
    for (int i = threadIdx.x; i < COUT; i += 256) bsh[i] = b[i];
    __syncthreads();
    const int total = n * COUT;
    for (int idx = blockIdx.x * 256 + threadIdx.x; idx < total; idx += gridDim.x * 256) {
        int row = idx / COUT;
        int c   = idx - row * COUT;
        const float* xr = X + (size_t)row * FIN;
        float acc = bsh[c];
        #pragma unroll
        for (int f = 0; f < FIN; ++f) acc = fmaf(xr[f], wsh[f * COUT + c], acc);
        if (ELU) acc = (acc > 0.f) ? acc : expm1f(acc);
        out[(size_t)row * COUT + c] = acc;
    }
}

// ---------- fc2 + log_softmax ----------
#define H1_DIM 128
#define NC_DIM 10
__global__ __launch_bounds__(256)
void head_kernel(const float* __restrict__ Hf, const float* __restrict__ W,
                 const float* __restrict__ b, float* __restrict__ out, int n)
{
    __shared__ float wsh[H1_DIM * NC_DIM];
    __shared__ float bsh[NC_DIM];
    for (int i = threadIdx.x; i < H1_DIM * NC_DIM; i += 256) wsh[i] = W[i];
    for (int i = threadIdx.x; i < NC_DIM; i += 256) bsh[i] = b[i];
    __syncthreads();
    for (int row = blockIdx.x * 256 + threadIdx.x; row < n; row += gridDim.x * 256) {
        const float* hr = Hf + (size_t)row * H1_DIM;
        float logit[NC_DIM];
        #pragma unroll
        for (int c = 0; c < NC_DIM; ++c) logit[c] = bsh[c];
        for (int f = 0; f < H1_DIM; ++f) {
            float xv = hr[f];
            #pragma unroll
            for (int c = 0; c < NC_DIM; ++c) logit[c] = fmaf(xv, wsh[f * NC_DIM + c], logit[c]);
        }
        float m = logit[0];
        #pragma unroll
        for (int c = 1; c < NC_DIM; ++c) m = fmaxf(m, logit[c]);
        float sum = 0.f;
        #pragma unroll
        for (int c = 0; c < NC_DIM; ++c) sum += __expf(logit[c] - m);
        float lse = m + logf(sum);
        #pragma unroll
        for (int c = 0; c < NC_DIM; ++c) out[(size_t)row * NC_DIM + c] = logit[c] - lse;
    }
}

extern "C" void kernel_launch(void* const* d_in, const int* in_sizes, int n_in,
                              void* d_out, int out_size, void* d_ws, size_t ws_size,
                              hipStream_t stream) {
    const float* x   = (const float*)d_in[0];
    const int*   ei  = (const int*)d_in[1];
    const float* ea  = (const float*)d_in[2];
    const float *Wq1 = (const float*)d_in[3],  *bq1 = (const float*)d_in[4];
    const float *Wk1 = (const float*)d_in[5],  *bk1 = (const float*)d_in[6];
    const float *Wv1 = (const float*)d_in[7],  *bv1 = (const float*)d_in[8];
    const float *We1 = (const float*)d_in[9],  *be1 = (const float*)d_in[10];
    const float *Ws1 = (const float*)d_in[11], *bs1 = (const float*)d_in[12];
    const float *Wq2 = (const float*)d_in[13], *bq2 = (const float*)d_in[14];
    const float *Wk2 = (const float*)d_in[15], *bk2 = (const float*)d_in[16];
    const float *Wv2 = (const float*)d_in[17], *bv2 = (const float*)d_in[18];
    const float *We2 = (const float*)d_in[19], *be2 = (const float*)d_in[20];
    const float *Ws2 = (const float*)d_in[21], *bs2 = (const float*)d_in[22];
    const float *Wf1 = (const float*)d_in[23], *bf1 = (const float*)d_in[24];
    const float *Wf2 = (const float*)d_in[25], *bf2 = (const float*)d_in[26];

    const int N = in_sizes[0] / 64;   // 100000
    const int E = in_sizes[2];        // 1600000
    const int* src = ei;              // edge_index[0]
    const int* dst = ei + E;          // edge_index[1]

    float* wsf = (float*)d_ws;
    const size_t N64 = (size_t)N * 64;
    float* q      = wsf;                      // N*64
    __half2* kv   = (__half2*)(q + N64);      // N*64 half2 (k,v packed) = N*64*4B
    float* s      = (float*)(kv + N64);       // N*64 (skip proj)
    float* h1     = s + N64;                  // N*32
    float* h2     = h1 + (size_t)N * 32;      // N*64
    int* deg      = (int*)(h2 + N64);         // N
    int* rowptr   = deg + N;                  // N+1
    int* bsum     = rowptr + N + 1;           // SCAN_NB
    int* boff     = bsum + SCAN_NB;           // SCAN_NB
    int* rank     = boff + SCAN_NB;           // E
    int2* ecsr    = (int2*)(rank + E);        // E (packed {src, eattr})
    float* hfc    = wsf;                      // N*128 (reuses dead q after conv2)

    float* out = (float*)d_out;

    // ---- CSR build ----
    hipMemsetAsync(deg, 0, (size_t)N * 4, stream);
    count_rank_kernel<<<2048, 256, 0, stream>>>(dst, deg, rank, E);
    blocksum_kernel<<<SCAN_NB, 256, 0, stream>>>(deg, bsum, N);
    scanb_kernel<<<1, 256, 0, stream>>>(bsum, boff, rowptr + N, SCAN_NB);
    writeptr_kernel<<<SCAN_NB, 256, 0, stream>>>(deg, boff, rowptr, N);
    fill_pack_kernel<<<4096, 256, 0, stream>>>(src, dst, ea, rowptr, rank, ecsr, E);

    const int convGrid = (N + 3) / 4;

    // ---- layer 1 (C=32) ----
    linear4_kernel<64, 32><<<2048, 256, 0, stream>>>(
        x, Wq1, bq1, Wk1, bk1, Wv1, bv1, Ws1, bs1, q, kv, s, N);
    conv_fused_kernel<32><<<convGrid, 256, 0, stream>>>(
        rowptr, ecsr, q, kv, s, We1, be1, h1, 0.17677669529663687f, N);

    // ---- layer 2 (C=64) ----
    linear4_kernel<32, 64><<<2048, 256, 0, stream>>>(
        h1, Wq2, bq2, Wk2, bk2, Wv2, bv2, Ws2, bs2, q, kv, s, N);
    conv_fused_kernel<64><<<convGrid, 256, 0, stream>>>(
        rowptr, ecsr, q, kv, s, We2, be2, h2, 0.125f, N);

    // ---- MLP head ----
    linear1_kernel<64, 128, true><<<2048, 256, 0, stream>>>(h2, Wf1, bf1, hfc, N);
    head_kernel<<<512, 256, 0, stream>>>(hfc, Wf2, bf2, out, N);
}